// Round 4
// baseline (688.947 us; speedup 1.0000x reference)
//
#include <hip/hip_runtime.h>
#include <math.h>

namespace {

constexpr int N   = 20000;
constexpr int E   = 250000;
constexpr int B   = 8;
constexpr int D   = 32;
constexpr int R2  = 100;
constexpr int L   = 6;
constexpr int NEG = 32;
constexpr float EPSF = 1e-6f;

constexpr int BD = B * D;        // 256
constexpr int NPB = 8;           // nodes per block in layer kernel
// bf16 hi/lo feat panels: [64 rows][136] shorts each (stride 136 = 16B-aligned
// rows, 68 dw = 4*17 -> 8 balanced bank-starts on b128 reads)
constexpr int PROW = 136;
constexpr int PLO  = 64 * PROW;              // lo panel offset (shorts)
// per-layer split-weight block (shorts): [wx_hi 1024 | wx_lo 1024 | wf_hi 12288 | wf_lo 12288]
constexpr int WSZ  = 26624;

typedef __attribute__((ext_vector_type(8))) short bf16x8;
typedef __attribute__((ext_vector_type(4))) float f32x4;

__device__ inline unsigned short f2bf(float x) {          // RNE f32->bf16
  unsigned int u = __float_as_uint(x);
  unsigned int r = u + 0x7FFF + ((u >> 16) & 1);
  return (unsigned short)(r >> 16);
}
__device__ inline float bf2f(unsigned short h) {
  return __uint_as_float(((unsigned int)h) << 16);
}
__device__ inline void split2(float v, unsigned short& hi, unsigned short& lo) {
  hi = f2bf(v);
  lo = f2bf(v - bf2f(hi));
}

// ---------------- init ----------------
__global__ void k_init(float* x0, int* cnt, int* fill, float* meanacc) {
  int i = blockIdx.x * blockDim.x + threadIdx.x;
  int stride = gridDim.x * blockDim.x;
  for (int t = i; t < N * BD; t += stride) x0[t] = 0.f;
  for (int t = i; t < N; t += stride) { cnt[t] = 0; fill[t] = 0; }
  if (i == 0) meanacc[0] = 0.f;
}

// query gather + boundary scatter (x0 must be zeroed first)
__global__ void k_query(const int* __restrict__ r_index, const int* __restrict__ h_index,
                        const float* __restrict__ query_emb, float* query, float* x0) {
  int tid = threadIdx.x;            // 256
  int b = tid >> 5, d = tid & 31;
  float q = query_emb[r_index[b] * D + d];
  query[tid] = q;
  x0[h_index[b] * BD + tid] = q;
}

__global__ void k_count(const int* __restrict__ edge_dst, int* cnt) {
  int e = blockIdx.x * blockDim.x + threadIdx.x;
  if (e < E) atomicAdd(&cnt[edge_dst[e]], 1);
}

// single-block exclusive scan over N counts -> row_start[N+1]
__global__ void k_scan(const int* __restrict__ cnt, int* row_start) {
  __shared__ int wsum[4];
  __shared__ int srun;
  int tid = threadIdx.x;            // 256
  int lane = tid & 63, wv = tid >> 6;
  if (tid == 0) srun = 0;
  __syncthreads();
  for (int base = 0; base < N; base += 256) {
    int i = base + tid;
    int v = (i < N) ? cnt[i] : 0;
    int x = v;
    for (int o = 1; o < 64; o <<= 1) {
      int y = __shfl_up(x, o, 64);
      if (lane >= o) x += y;
    }
    if (lane == 63) wsum[wv] = x;
    __syncthreads();
    int add = 0;
    for (int w = 0; w < wv; ++w) add += wsum[w];
    int excl = x - v + add;
    if (i < N) row_start[i] = srun + excl;
    int tot = wsum[0] + wsum[1] + wsum[2] + wsum[3];
    __syncthreads();
    if (tid == 0) srun += tot;
    __syncthreads();
  }
  if (tid == 0) row_start[N] = srun;   // == E
}

// scatter edges into CSR slots; pack src | (type<<16)
__global__ void k_scatter(const int* __restrict__ edge_src, const int* __restrict__ edge_dst,
                          const int* __restrict__ edge_type, const int* __restrict__ row_start,
                          int* fill, int* packed) {
  int e = blockIdx.x * blockDim.x + threadIdx.x;
  if (e < E) {
    int dn = edge_dst[e];
    int pos = atomicAdd(&fill[dn], 1);
    packed[row_start[dn] + pos] = edge_src[e] | (edge_type[e] << 16);
  }
}

__global__ void k_logsum(const int* __restrict__ cnt, float* meanacc) {
  int i = blockIdx.x * blockDim.x + threadIdx.x;
  float v = (i < N) ? logf((float)(cnt[i] + 1)) : 0.f;
  for (int o = 32; o > 0; o >>= 1) v += __shfl_down(v, o, 64);
  __shared__ float ws4[4];
  int lane = threadIdx.x & 63, wv = threadIdx.x >> 6;
  if (lane == 0) ws4[wv] = v;
  __syncthreads();
  if (threadIdx.x == 0) atomicAdd(meanacc, ws4[0] + ws4[1] + ws4[2] + ws4[3]);
}

__global__ void k_scales(const int* __restrict__ cnt, const float* __restrict__ meanacc,
                         float* scales) {
  int i = blockIdx.x * blockDim.x + threadIdx.x;
  if (i < N) {
    float m = meanacc[0] / (float)N;
    float s = logf((float)(cnt[i] + 1)) / m;
    scales[i * 3 + 0] = 1.f;
    scales[i * 3 + 1] = s;
    scales[i * 3 + 2] = 1.f / fmaxf(s, 0.01f);
  }
}

// rel[l][b][r][d] = br[l][r*D+d] + sum_k query[b][k] * Wr[l][r*D+d][k]
__global__ void k_rel(const float* __restrict__ query, const float* __restrict__ Wr,
                      const float* __restrict__ br, float* rel) {
  int o = blockIdx.x * blockDim.x + threadIdx.x;
  if (o >= L * B * R2 * D) return;
  int d = o & 31;
  int r = (o >> 5) % R2;
  int b = (o / (R2 * D)) % B;
  int l = o / (B * R2 * D);
  int rd = r * D + d;
  const float4* wrow = (const float4*)(Wr + ((size_t)l * R2 * D + rd) * D);
  const float* q = query + b * D;
  float acc = br[l * R2 * D + rd];
#pragma unroll
  for (int k = 0; k < 8; ++k) {
    float4 w4 = wrow[k];
    acc = fmaf(q[4 * k + 0], w4.x, acc);
    acc = fmaf(q[4 * k + 1], w4.y, acc);
    acc = fmaf(q[4 * k + 2], w4.z, acc);
    acc = fmaf(q[4 * k + 3], w4.w, acc);
  }
  rel[o] = acc;
}

// split weights to bf16 hi/lo, k-contiguous per output column:
//  k<32 (x part):     wx_[j*32 + k]
//  k=32+3f+s (feat):  wf_[(s*32 + j)*128 + f]
__global__ void k_wt(const float* __restrict__ Wl, short* WT) {
  int o = blockIdx.x * blockDim.x + threadIdx.x;
  if (o >= L * 13312) return;
  int l = o / 13312, t = o % 13312;
  int j = t / 416, k = t % 416;
  float v = Wl[(size_t)l * 13312 + j * 416 + k];
  unsigned short hi, lo;
  split2(v, hi, lo);
  short* wt = WT + (size_t)l * WSZ;
  if (k < 32) {
    int dx = j * 32 + k;
    wt[dx] = (short)hi;
    wt[1024 + dx] = (short)lo;
  } else {
    int u = k - 32;
    int f = u / 3, s = u % 3;
    int df = (s * 32 + j) * 128 + f;
    wt[2048 + df] = (short)hi;
    wt[14336 + df] = (short)lo;
  }
}

// ---- fused layer kernel: 8 nodes / block, 512 threads (8 waves) ----
// Phase 1 (agg): halves process 4 nodes each; stats split to bf16 hi/lo and
// written row-major to LDS panels [64][136].
// Phase 2 (GEMM): bf16x3 MFMA 16x16x32; 8 C-tiles of 16x16, one per wave
// (mt=wv>>1, nt=wv&1) -> NO cross-wave reduction, one barrier total.
// Scale identity: out = x@Wx^T + sum_s scale_s(row) * (F@W_s^T), scales in epilogue.
__global__ __launch_bounds__(512, 8) void k_layer(
    const float* __restrict__ xin, float* __restrict__ xout,
    const float* __restrict__ rel_l, const short* __restrict__ WT_l,
    const float* __restrict__ bl_l, const float* __restrict__ scales,
    const int* __restrict__ row_start, const int* __restrict__ packed,
    const int* __restrict__ h_index, const float* __restrict__ query) {
  __shared__ __align__(16) short pan[2 * 64 * PROW];   // 34,816 B

  int tid = threadIdx.x;
  int ch = tid & 255;
  int b = ch >> 5, d = ch & 31;
  int half = __builtin_amdgcn_readfirstlane(tid >> 8);  // wave-uniform 0/1
  int node0 = blockIdx.x * NPB;

  int hb = h_index[b];
  float qv = query[ch];
  const float* relb = rel_l + b * (R2 * D) + d;

  // -------- aggregation: this half handles nodes node0 + half*4 + [0,4) --------
  for (int nn = 0; nn < 4; ++nn) {
    int node = node0 + half * 4 + nn;
    int rs = row_start[node];
    int cntE = row_start[node + 1] - rs;
    float s1 = 0.f, s2 = 0.f;
    float mx = -INFINITY, mn = INFINITY;
    int j = 0;
    for (; j + 3 < cntE; j += 4) {       // 4 gathers in flight
      int pk0 = packed[rs + j];          // wave-uniform -> scalar loads
      int pk1 = packed[rs + j + 1];
      int pk2 = packed[rs + j + 2];
      int pk3 = packed[rs + j + 3];
      float xv0 = xin[(pk0 & 0xFFFF) * BD + ch];
      float xv1 = xin[(pk1 & 0xFFFF) * BD + ch];
      float xv2 = xin[(pk2 & 0xFFFF) * BD + ch];
      float xv3 = xin[(pk3 & 0xFFFF) * BD + ch];
      float rv0 = relb[(pk0 >> 16) * D];
      float rv1 = relb[(pk1 >> 16) * D];
      float rv2 = relb[(pk2 >> 16) * D];
      float rv3 = relb[(pk3 >> 16) * D];
      float m0 = xv0 * rv0, m1 = xv1 * rv1, m2 = xv2 * rv2, m3 = xv3 * rv3;
      s1 += m0; s2 = fmaf(m0, m0, s2); mx = fmaxf(mx, m0); mn = fminf(mn, m0);
      s1 += m1; s2 = fmaf(m1, m1, s2); mx = fmaxf(mx, m1); mn = fminf(mn, m1);
      s1 += m2; s2 = fmaf(m2, m2, s2); mx = fmaxf(mx, m2); mn = fminf(mn, m2);
      s1 += m3; s2 = fmaf(m3, m3, s2); mx = fmaxf(mx, m3); mn = fminf(mn, m3);
    }
    for (; j < cntE; ++j) {
      int pk = packed[rs + j];
      float xv = xin[(pk & 0xFFFF) * BD + ch];
      float rv = relb[(pk >> 16) * D];
      float m = xv * rv;
      s1 += m; s2 = fmaf(m, m, s2);
      mx = fmaxf(mx, m); mn = fminf(mn, m);
    }
    float bnd = (hb == node) ? qv : 0.f;   // boundary self-message
    s1 += bnd;
    s2 = fmaf(bnd, bnd, s2);
    mx = fmaxf(mx, bnd);
    mn = fminf(mn, bnd);
    float invdeg = 1.f / (float)(cntE + 1);
    float mean = s1 * invdeg;
    float sqm = s2 * invdeg;
    float sd = sqrtf(fmaxf(sqm - mean * mean, EPSF));

    // split stats to bf16 hi/lo; f = 4d + st
    unsigned short h0, l0, h1, l1, h2, l2, h3, l3;
    split2(mean, h0, l0);
    split2(mx, h1, l1);
    split2(mn, h2, l2);
    split2(sd, h3, l3);
    int r = (half * 4 + nn) * 8 + b;       // row = node_local*8 + b
    int po = r * PROW + 4 * d;             // shorts; byte ofs r*272+8d (8B aligned)
    uint2 qh, ql;
    qh.x = (unsigned int)h0 | ((unsigned int)h1 << 16);
    qh.y = (unsigned int)h2 | ((unsigned int)h3 << 16);
    ql.x = (unsigned int)l0 | ((unsigned int)l1 << 16);
    ql.y = (unsigned int)l2 | ((unsigned int)l3 << 16);
    *(uint2*)&pan[po] = qh;
    *(uint2*)&pan[PLO + po] = ql;
  }
  __syncthreads();

  // -------- GEMM: one 16x16 C-tile per wave, bf16x3 MFMA --------
  int lane = tid & 63;
  int wv = __builtin_amdgcn_readfirstlane(tid >> 6);   // 0..7
  int mt = wv >> 1, nt = wv & 1;
  int li = lane & 15, kg = lane >> 4;      // A-row / B-col index, k-group
  int rowA = mt * 16 + li;                 // this lane's A row
  int j = nt * 16 + li;                    // this lane's B column (output dim)

  const short* wxh = WT_l;
  const short* wxl = WT_l + 1024;
  const short* wfh = WT_l + 2048;
  const short* wfl = WT_l + 14336;

  f32x4 acc0 = {0.f, 0.f, 0.f, 0.f};
  f32x4 acc1 = {0.f, 0.f, 0.f, 0.f};
  f32x4 acc2 = {0.f, 0.f, 0.f, 0.f};

  // x-part (K=32, one step): A from global (own rows), split in-register
  {
    int xb = node0 * 256 + rowA * 32 + kg * 8;
    float4 xv0 = *(const float4*)&xin[xb];
    float4 xv1 = *(const float4*)&xin[xb + 4];
    float xs[8] = {xv0.x, xv0.y, xv0.z, xv0.w, xv1.x, xv1.y, xv1.z, xv1.w};
    bf16x8 ah, al;
#pragma unroll
    for (int i = 0; i < 8; ++i) {
      unsigned short h, lo;
      split2(xs[i], h, lo);
      ah[i] = (short)h;
      al[i] = (short)lo;
    }
    int wo = j * 32 + kg * 8;
    bf16x8 bh = *(const bf16x8*)&wxh[wo];
    bf16x8 bl = *(const bf16x8*)&wxl[wo];
    acc0 = __builtin_amdgcn_mfma_f32_16x16x32_bf16(al, bh, acc0, 0, 0, 0);
    acc0 = __builtin_amdgcn_mfma_f32_16x16x32_bf16(ah, bl, acc0, 0, 0, 0);
    acc0 = __builtin_amdgcn_mfma_f32_16x16x32_bf16(ah, bh, acc0, 0, 0, 0);
  }

  // feat part: K=128 in 4 steps; A-frags shared across the 3 scale-segments
  const short* ph = &pan[rowA * PROW];
  const short* pl = &pan[PLO + rowA * PROW];
#pragma unroll
  for (int step = 0; step < 4; ++step) {
    bf16x8 ah = *(const bf16x8*)&ph[step * 32 + kg * 8];
    bf16x8 al = *(const bf16x8*)&pl[step * 32 + kg * 8];
    int fo = j * 128 + step * 32 + kg * 8;
    {
      bf16x8 bh = *(const bf16x8*)&wfh[fo];
      bf16x8 bl = *(const bf16x8*)&wfl[fo];
      acc0 = __builtin_amdgcn_mfma_f32_16x16x32_bf16(al, bh, acc0, 0, 0, 0);
      acc0 = __builtin_amdgcn_mfma_f32_16x16x32_bf16(ah, bl, acc0, 0, 0, 0);
      acc0 = __builtin_amdgcn_mfma_f32_16x16x32_bf16(ah, bh, acc0, 0, 0, 0);
    }
    {
      bf16x8 bh = *(const bf16x8*)&wfh[4096 + fo];
      bf16x8 bl = *(const bf16x8*)&wfl[4096 + fo];
      acc1 = __builtin_amdgcn_mfma_f32_16x16x32_bf16(al, bh, acc1, 0, 0, 0);
      acc1 = __builtin_amdgcn_mfma_f32_16x16x32_bf16(ah, bl, acc1, 0, 0, 0);
      acc1 = __builtin_amdgcn_mfma_f32_16x16x32_bf16(ah, bh, acc1, 0, 0, 0);
    }
    {
      bf16x8 bh = *(const bf16x8*)&wfh[8192 + fo];
      bf16x8 bl = *(const bf16x8*)&wfl[8192 + fo];
      acc2 = __builtin_amdgcn_mfma_f32_16x16x32_bf16(al, bh, acc2, 0, 0, 0);
      acc2 = __builtin_amdgcn_mfma_f32_16x16x32_bf16(ah, bl, acc2, 0, 0, 0);
      acc2 = __builtin_amdgcn_mfma_f32_16x16x32_bf16(ah, bh, acc2, 0, 0, 0);
    }
  }

  // -------- epilogue: scales per row, bias, relu, store --------
  // C/D layout (verified m89/m91): col = lane&15, row = (lane>>4)*4 + reg
  {
    int rbase = mt * 16 + kg * 4;          // rows rbase..rbase+3, single node
    int node = node0 + (rbase >> 3);
    float sc1 = scales[node * 3 + 1];
    float sc2 = scales[node * 3 + 2];
    float bias = bl_l[j & 31];             // j = nt*16 + li < 32
#pragma unroll
    for (int reg = 0; reg < 4; ++reg) {
      float v = acc0[reg] + sc1 * acc1[reg] + sc2 * acc2[reg] + bias;
      xout[node0 * 256 + (rbase + reg) * 32 + j] = fmaxf(v, 0.f);
    }
  }
}

// -------------- scoring head: one block per (b, neg) --------------
__global__ void k_score(const float* __restrict__ xL, const float* __restrict__ query,
                        const int* __restrict__ t_index, const float* __restrict__ W1,
                        const float* __restrict__ b1, const float* __restrict__ W2,
                        const float* __restrict__ b2, float* outp) {
  int bn = blockIdx.x;             // b*NEG + neg
  int b = bn >> 5;
  int j = threadIdx.x;             // 64
  __shared__ float f[64];
  int t = t_index[bn];
  f[j] = (j < 32) ? xL[t * BD + b * D + j] : query[b * D + (j - 32)];
  __syncthreads();
  const float* w1r = W1 + j * 64;
  float h = b1[j];
#pragma unroll
  for (int k = 0; k < 64; ++k) h = fmaf(f[k], w1r[k], h);
  h = fmaxf(h, 0.f);
  float p = h * W2[j];
#pragma unroll
  for (int o = 32; o > 0; o >>= 1) p += __shfl_down(p, o, 64);
  if (j == 0) outp[bn] = p + b2[0];
}

} // namespace

extern "C" void kernel_launch(void* const* d_in, const int* in_sizes, int n_in,
                              void* d_out, int out_size, void* d_ws, size_t ws_size,
                              hipStream_t stream) {
  const int* edge_src   = (const int*)d_in[0];
  const int* edge_dst   = (const int*)d_in[1];
  const int* edge_type  = (const int*)d_in[2];
  const int* h_index    = (const int*)d_in[3];
  const int* t_index    = (const int*)d_in[4];
  const int* r_index    = (const int*)d_in[5];
  const float* query_emb= (const float*)d_in[6];
  const float* Wr       = (const float*)d_in[7];
  const float* br       = (const float*)d_in[8];
  const float* Wl       = (const float*)d_in[9];
  const float* bl       = (const float*)d_in[10];
  const float* W1       = (const float*)d_in[11];
  const float* b1       = (const float*)d_in[12];
  const float* W2       = (const float*)d_in[13];
  const float* b2       = (const float*)d_in[14];
  float* outp = (float*)d_out;
  (void)in_sizes; (void)n_in; (void)out_size; (void)ws_size;

  char* w = (char*)d_ws;
  auto alloc = [&](size_t bytes) {
    char* p = w;
    w += (bytes + 511) & ~(size_t)511;
    return p;
  };
  float* x0      = (float*)alloc(sizeof(float) * N * BD);
  float* x1      = (float*)alloc(sizeof(float) * N * BD);
  float* rel     = (float*)alloc(sizeof(float) * L * B * R2 * D);
  short* WT      = (short*)alloc(sizeof(short) * L * WSZ);
  float* query   = (float*)alloc(sizeof(float) * BD);
  float* scales  = (float*)alloc(sizeof(float) * N * 3);
  float* meanacc = (float*)alloc(sizeof(float) * 16);
  int* row_start = (int*)alloc(sizeof(int) * (N + 1));
  int* cnt       = (int*)alloc(sizeof(int) * N);
  int* fill      = (int*)alloc(sizeof(int) * N);
  int* packed    = (int*)alloc(sizeof(int) * E);

  k_init<<<2048, 256, 0, stream>>>(x0, cnt, fill, meanacc);
  k_query<<<1, 256, 0, stream>>>(r_index, h_index, query_emb, query, x0);
  k_count<<<(E + 255) / 256, 256, 0, stream>>>(edge_dst, cnt);
  k_scan<<<1, 256, 0, stream>>>(cnt, row_start);
  k_scatter<<<(E + 255) / 256, 256, 0, stream>>>(edge_src, edge_dst, edge_type,
                                                 row_start, fill, packed);
  k_logsum<<<(N + 255) / 256, 256, 0, stream>>>(cnt, meanacc);
  k_scales<<<(N + 255) / 256, 256, 0, stream>>>(cnt, meanacc, scales);
  k_rel<<<(L * B * R2 * D + 255) / 256, 256, 0, stream>>>(query, Wr, br, rel);
  k_wt<<<(L * 13312 + 255) / 256, 256, 0, stream>>>(Wl, WT);

  const float* xin = x0;
  float* xout = x1;
  for (int l = 0; l < L; ++l) {
    k_layer<<<N / NPB, 512, 0, stream>>>(xin, xout,
        rel + (size_t)l * B * R2 * D, WT + (size_t)l * WSZ, bl + l * D,
        scales, row_start, packed, h_index, query);
    const float* t = xout;
    xout = (float*)xin;
    xin = t;
  }
  // L is even -> final activations are back in x0 (== xin after last swap)
  k_score<<<B * NEG, 64, 0, stream>>>(xin, query, t_index, W1, b1, W2, b2, outp);
}

// Round 5
// 596.913 us; speedup vs baseline: 1.1542x; 1.1542x over previous
//
#include <hip/hip_runtime.h>
#include <math.h>

namespace {

constexpr int N   = 20000;
constexpr int E   = 250000;
constexpr int B   = 8;
constexpr int D   = 32;
constexpr int R2  = 100;
constexpr int L   = 6;
constexpr int NEG = 32;
constexpr float EPSF = 1e-6f;

constexpr int BD = B * D;        // 256
constexpr int NPB = 8;           // nodes per block in layer kernel
// bf16 hi/lo feat panels: [64 rows][136] shorts each
constexpr int PROW = 136;
constexpr int PLO  = 64 * PROW;  // lo panel offset (shorts)
// per-layer split-weight block (shorts): [wx_hi 1024 | wx_lo 1024 | wf_hi 12288 | wf_lo 12288]
constexpr int WSZ  = 26624;
constexpr int NSCB = (N + 255) / 256;   // scan blocks = 79

typedef __attribute__((ext_vector_type(8))) short bf16x8;
typedef __attribute__((ext_vector_type(4))) float f32x4;

__device__ inline unsigned short f2bf(float x) {          // RNE f32->bf16
  unsigned int u = __float_as_uint(x);
  unsigned int r = u + 0x7FFF + ((u >> 16) & 1);
  return (unsigned short)(r >> 16);
}
__device__ inline float bf2f(unsigned short h) {
  return __uint_as_float(((unsigned int)h) << 16);
}
__device__ inline void split2(float v, unsigned short& hi, unsigned short& lo) {
  hi = f2bf(v);
  lo = f2bf(v - bf2f(hi));
}

// ---------------- init ----------------
__global__ void k_init(float* x0, int* cnt, float* meanacc) {
  int i = blockIdx.x * blockDim.x + threadIdx.x;
  int stride = gridDim.x * blockDim.x;
  for (int t = i; t < N * BD; t += stride) x0[t] = 0.f;
  for (int t = i; t < N; t += stride) cnt[t] = 0;
  if (i == 0) meanacc[0] = 0.f;
}

// query gather + boundary scatter (x0 must be zeroed first)
__global__ void k_query(const int* __restrict__ r_index, const int* __restrict__ h_index,
                        const float* __restrict__ query_emb, float* query, float* x0) {
  int tid = threadIdx.x;            // 256
  int b = tid >> 5, d = tid & 31;
  float q = query_emb[r_index[b] * D + d];
  query[tid] = q;
  x0[h_index[b] * BD + tid] = q;
}

__global__ void k_count(const int* __restrict__ edge_dst, int* cnt) {
  int e = blockIdx.x * blockDim.x + threadIdx.x;
  if (e < E) atomicAdd(&cnt[edge_dst[e]], 1);
}

// multi-block exclusive scan: A) per-block local scan + block sums
__global__ void k_scanA(const int* __restrict__ cnt, int* row_start, int* bsum) {
  __shared__ int wsum[4];
  int tid = threadIdx.x;            // 256
  int lane = tid & 63, wv = tid >> 6;
  int i = blockIdx.x * 256 + tid;
  int v = (i < N) ? cnt[i] : 0;
  int x = v;
  for (int o = 1; o < 64; o <<= 1) {
    int y = __shfl_up(x, o, 64);
    if (lane >= o) x += y;
  }
  if (lane == 63) wsum[wv] = x;
  __syncthreads();
  int add = 0;
  for (int w = 0; w < wv; ++w) add += wsum[w];
  if (i < N) row_start[i] = x - v + add;     // block-local exclusive
  if (tid == 255) bsum[blockIdx.x] = add + x; // block total
}

// B) scan the block sums (1 wave handles up to 128 blocks)
__global__ void k_scanB(const int* __restrict__ bsum, int* boff, int* row_start) {
  int lane = threadIdx.x;           // 64
  int a0 = (lane < NSCB) ? bsum[lane] : 0;
  int a1 = (64 + lane < NSCB) ? bsum[64 + lane] : 0;
  int x = a0;
  for (int o = 1; o < 64; o <<= 1) {
    int y = __shfl_up(x, o, 64);
    if (lane >= o) x += y;
  }
  int tot0 = __shfl(x, 63, 64);
  int x1 = a1;
  for (int o = 1; o < 64; o <<= 1) {
    int y = __shfl_up(x1, o, 64);
    if (lane >= o) x1 += y;
  }
  if (lane < NSCB) boff[lane] = x - a0;
  if (64 + lane < NSCB) boff[64 + lane] = tot0 + x1 - a1;
  if (lane == 63) row_start[N] = tot0 + __shfl(x1, 63, 64);   // == E
}

// C) add block offsets
__global__ void k_scanC(int* row_start, const int* __restrict__ boff) {
  int i = blockIdx.x * 256 + threadIdx.x;
  if (i < N) row_start[i] += boff[blockIdx.x];
}

// scatter edges into CSR slots; pack src | (type<<16)
__global__ void k_scatter(const int* __restrict__ edge_src, const int* __restrict__ edge_dst,
                          const int* __restrict__ edge_type, const int* __restrict__ row_start,
                          int* fill, int* packed) {
  int e = blockIdx.x * blockDim.x + threadIdx.x;
  if (e < E) {
    int dn = edge_dst[e];
    int pos = atomicAdd(&fill[dn], 1);
    packed[row_start[dn] + pos] = edge_src[e] | (edge_type[e] << 16);
  }
}

__global__ void k_fill0(int* fill) {
  int i = blockIdx.x * blockDim.x + threadIdx.x;
  if (i < N) fill[i] = 0;
}

__global__ void k_logsum(const int* __restrict__ cnt, float* meanacc) {
  int i = blockIdx.x * blockDim.x + threadIdx.x;
  float v = (i < N) ? logf((float)(cnt[i] + 1)) : 0.f;
  for (int o = 32; o > 0; o >>= 1) v += __shfl_down(v, o, 64);
  __shared__ float ws4[4];
  int lane = threadIdx.x & 63, wv = threadIdx.x >> 6;
  if (lane == 0) ws4[wv] = v;
  __syncthreads();
  if (threadIdx.x == 0) atomicAdd(meanacc, ws4[0] + ws4[1] + ws4[2] + ws4[3]);
}

__global__ void k_scales(const int* __restrict__ cnt, const float* __restrict__ meanacc,
                         float* scales) {
  int i = blockIdx.x * blockDim.x + threadIdx.x;
  if (i < N) {
    float m = meanacc[0] / (float)N;
    float s = logf((float)(cnt[i] + 1)) / m;
    scales[i * 3 + 0] = 1.f;
    scales[i * 3 + 1] = s;
    scales[i * 3 + 2] = 1.f / fmaxf(s, 0.01f);
  }
}

// rel[l][b][r][d] = br[l][r*D+d] + sum_k query[b][k] * Wr[l][r*D+d][k]
__global__ void k_rel(const float* __restrict__ query, const float* __restrict__ Wr,
                      const float* __restrict__ br, float* rel) {
  int o = blockIdx.x * blockDim.x + threadIdx.x;
  if (o >= L * B * R2 * D) return;
  int d = o & 31;
  int r = (o >> 5) % R2;
  int b = (o / (R2 * D)) % B;
  int l = o / (B * R2 * D);
  int rd = r * D + d;
  const float4* wrow = (const float4*)(Wr + ((size_t)l * R2 * D + rd) * D);
  const float* q = query + b * D;
  float acc = br[l * R2 * D + rd];
#pragma unroll
  for (int k = 0; k < 8; ++k) {
    float4 w4 = wrow[k];
    acc = fmaf(q[4 * k + 0], w4.x, acc);
    acc = fmaf(q[4 * k + 1], w4.y, acc);
    acc = fmaf(q[4 * k + 2], w4.z, acc);
    acc = fmaf(q[4 * k + 3], w4.w, acc);
  }
  rel[o] = acc;
}

// split weights to bf16 hi/lo, k-contiguous per output column:
//  k<32 (x part):     wx_[j*32 + k]
//  k=32+3f+s (feat):  wf_[(s*32 + j)*128 + f]
__global__ void k_wt(const float* __restrict__ Wl, short* WT) {
  int o = blockIdx.x * blockDim.x + threadIdx.x;
  if (o >= L * 13312) return;
  int l = o / 13312, t = o % 13312;
  int j = t / 416, k = t % 416;
  float v = Wl[(size_t)l * 13312 + j * 416 + k];
  unsigned short hi, lo;
  split2(v, hi, lo);
  short* wt = WT + (size_t)l * WSZ;
  if (k < 32) {
    int dx = j * 32 + k;
    wt[dx] = (short)hi;
    wt[1024 + dx] = (short)lo;
  } else {
    int u = k - 32;
    int f = u / 3, s = u % 3;
    int df = (s * 32 + j) * 128 + f;
    wt[2048 + df] = (short)hi;
    wt[14336 + df] = (short)lo;
  }
}

// ---- fused layer kernel: 8 nodes / block, 512 threads (8 waves) ----
// Phase 1 (agg): ONE WAVE PER NODE; lane covers 4 consecutive channels as
// float4 -> one 1KB x-row gather per instruction, 4 edges in flight,
// 8 nodes fully concurrent. Stats split bf16 hi/lo into LDS panels [64][136].
// Phase 2 (GEMM): bf16x3 MFMA 16x16x32; one 16x16 C-tile per wave; scale
// identity out = x@Wx^T + sum_s scale_s(row)*(F@W_s^T), scales in epilogue.
__global__ __launch_bounds__(512, 8) void k_layer(
    const float* __restrict__ xin, float* __restrict__ xout,
    const float* __restrict__ rel_l, const short* __restrict__ WT_l,
    const float* __restrict__ bl_l, const float* __restrict__ scales,
    const int* __restrict__ row_start, const int* __restrict__ packed,
    const int* __restrict__ h_index, const float* __restrict__ query) {
  __shared__ __align__(16) short pan[2 * 64 * PROW];   // 34,816 B

  int tid = threadIdx.x;
  int lane = tid & 63;
  int wv = __builtin_amdgcn_readfirstlane(tid >> 6);   // 0..7, wave-uniform
  int node0 = blockIdx.x * NPB;

  // -------- aggregation: wave wv owns node node0+wv --------
  {
    int ch4 = 4 * lane;                 // channels ch4..ch4+3
    int b = lane >> 3;
    int d0 = ch4 & 31;                  // = 4*(lane&7)
    int node = node0 + wv;
    int hb = h_index[b];
    const float* relb4 = rel_l + b * (R2 * D) + d0;
    const float* xch = xin + ch4;
    int rs = row_start[node];
    int cntE = row_start[node + 1] - rs;

    float4 s1 = {0.f, 0.f, 0.f, 0.f}, s2 = {0.f, 0.f, 0.f, 0.f};
    float4 mx = {-INFINITY, -INFINITY, -INFINITY, -INFINITY};
    float4 mn = {INFINITY, INFINITY, INFINITY, INFINITY};

    auto acc4 = [&](float4 xv, float4 rv) {
      float m0 = xv.x * rv.x, m1 = xv.y * rv.y, m2 = xv.z * rv.z, m3 = xv.w * rv.w;
      s1.x += m0; s2.x = fmaf(m0, m0, s2.x); mx.x = fmaxf(mx.x, m0); mn.x = fminf(mn.x, m0);
      s1.y += m1; s2.y = fmaf(m1, m1, s2.y); mx.y = fmaxf(mx.y, m1); mn.y = fminf(mn.y, m1);
      s1.z += m2; s2.z = fmaf(m2, m2, s2.z); mx.z = fmaxf(mx.z, m2); mn.z = fminf(mn.z, m2);
      s1.w += m3; s2.w = fmaf(m3, m3, s2.w); mx.w = fmaxf(mx.w, m3); mn.w = fminf(mn.w, m3);
    };

    int j = 0;
    for (; j + 3 < cntE; j += 4) {        // 4 edges (8 float4 loads) in flight
      int pk0 = packed[rs + j + 0];       // uniform -> s_load_dwordx4
      int pk1 = packed[rs + j + 1];
      int pk2 = packed[rs + j + 2];
      int pk3 = packed[rs + j + 3];
      float4 xv0 = *(const float4*)&xch[(pk0 & 0xFFFF) * BD];
      float4 xv1 = *(const float4*)&xch[(pk1 & 0xFFFF) * BD];
      float4 xv2 = *(const float4*)&xch[(pk2 & 0xFFFF) * BD];
      float4 xv3 = *(const float4*)&xch[(pk3 & 0xFFFF) * BD];
      float4 rv0 = *(const float4*)&relb4[(pk0 >> 16) * D];
      float4 rv1 = *(const float4*)&relb4[(pk1 >> 16) * D];
      float4 rv2 = *(const float4*)&relb4[(pk2 >> 16) * D];
      float4 rv3 = *(const float4*)&relb4[(pk3 >> 16) * D];
      acc4(xv0, rv0);
      acc4(xv1, rv1);
      acc4(xv2, rv2);
      acc4(xv3, rv3);
    }
    for (; j < cntE; ++j) {
      int pk = packed[rs + j];
      float4 xv = *(const float4*)&xch[(pk & 0xFFFF) * BD];
      float4 rv = *(const float4*)&relb4[(pk >> 16) * D];
      acc4(xv, rv);
    }
    // boundary self-message
    {
      float4 qv = *(const float4*)&query[ch4];
      float4 one = {1.f, 1.f, 1.f, 1.f};
      float4 bnd;
      bool isb = (hb == node);
      bnd.x = isb ? qv.x : 0.f;
      bnd.y = isb ? qv.y : 0.f;
      bnd.z = isb ? qv.z : 0.f;
      bnd.w = isb ? qv.w : 0.f;
      acc4(bnd, one);
    }
    float invdeg = 1.f / (float)(cntE + 1);

    unsigned int hw[8], lw[8];
    {
      float mean = s1.x * invdeg, sq = s2.x * invdeg;
      float sd = sqrtf(fmaxf(sq - mean * mean, EPSF));
      unsigned short h0, l0, h1, l1, h2, l2, h3, l3;
      split2(mean, h0, l0); split2(mx.x, h1, l1); split2(mn.x, h2, l2); split2(sd, h3, l3);
      hw[0] = (unsigned)h0 | ((unsigned)h1 << 16); hw[1] = (unsigned)h2 | ((unsigned)h3 << 16);
      lw[0] = (unsigned)l0 | ((unsigned)l1 << 16); lw[1] = (unsigned)l2 | ((unsigned)l3 << 16);
    }
    {
      float mean = s1.y * invdeg, sq = s2.y * invdeg;
      float sd = sqrtf(fmaxf(sq - mean * mean, EPSF));
      unsigned short h0, l0, h1, l1, h2, l2, h3, l3;
      split2(mean, h0, l0); split2(mx.y, h1, l1); split2(mn.y, h2, l2); split2(sd, h3, l3);
      hw[2] = (unsigned)h0 | ((unsigned)h1 << 16); hw[3] = (unsigned)h2 | ((unsigned)h3 << 16);
      lw[2] = (unsigned)l0 | ((unsigned)l1 << 16); lw[3] = (unsigned)l2 | ((unsigned)l3 << 16);
    }
    {
      float mean = s1.z * invdeg, sq = s2.z * invdeg;
      float sd = sqrtf(fmaxf(sq - mean * mean, EPSF));
      unsigned short h0, l0, h1, l1, h2, l2, h3, l3;
      split2(mean, h0, l0); split2(mx.z, h1, l1); split2(mn.z, h2, l2); split2(sd, h3, l3);
      hw[4] = (unsigned)h0 | ((unsigned)h1 << 16); hw[5] = (unsigned)h2 | ((unsigned)h3 << 16);
      lw[4] = (unsigned)l0 | ((unsigned)l1 << 16); lw[5] = (unsigned)l2 | ((unsigned)l3 << 16);
    }
    {
      float mean = s1.w * invdeg, sq = s2.w * invdeg;
      float sd = sqrtf(fmaxf(sq - mean * mean, EPSF));
      unsigned short h0, l0, h1, l1, h2, l2, h3, l3;
      split2(mean, h0, l0); split2(mx.w, h1, l1); split2(mn.w, h2, l2); split2(sd, h3, l3);
      hw[6] = (unsigned)h0 | ((unsigned)h1 << 16); hw[7] = (unsigned)h2 | ((unsigned)h3 << 16);
      lw[6] = (unsigned)l0 | ((unsigned)l1 << 16); lw[7] = (unsigned)l2 | ((unsigned)l3 << 16);
    }
    int r = wv * 8 + b;                  // panel row
    short* dh = &pan[r * PROW + 4 * d0];       // 16B aligned
    short* dl = &pan[PLO + r * PROW + 4 * d0];
    *(uint4*)dh = make_uint4(hw[0], hw[1], hw[2], hw[3]);
    *(uint4*)(dh + 8) = make_uint4(hw[4], hw[5], hw[6], hw[7]);
    *(uint4*)dl = make_uint4(lw[0], lw[1], lw[2], lw[3]);
    *(uint4*)(dl + 8) = make_uint4(lw[4], lw[5], lw[6], lw[7]);
  }
  __syncthreads();

  // -------- GEMM: one 16x16 C-tile per wave, bf16x3 MFMA --------
  int mt = wv >> 1, nt = wv & 1;
  int li = lane & 15, kg = lane >> 4;      // A-row / B-col index, k-group
  int rowA = mt * 16 + li;                 // this lane's A row
  int jc = nt * 16 + li;                   // this lane's B column (output dim)

  const short* wxh = WT_l;
  const short* wxl = WT_l + 1024;
  const short* wfh = WT_l + 2048;
  const short* wfl = WT_l + 14336;

  f32x4 acc0 = {0.f, 0.f, 0.f, 0.f};
  f32x4 acc1 = {0.f, 0.f, 0.f, 0.f};
  f32x4 acc2 = {0.f, 0.f, 0.f, 0.f};

  // x-part (K=32, one step): A from global (own rows), split in-register
  {
    int xb = node0 * 256 + rowA * 32 + kg * 8;
    float4 xv0 = *(const float4*)&xin[xb];
    float4 xv1 = *(const float4*)&xin[xb + 4];
    float xs[8] = {xv0.x, xv0.y, xv0.z, xv0.w, xv1.x, xv1.y, xv1.z, xv1.w};
    bf16x8 ah, al;
#pragma unroll
    for (int i = 0; i < 8; ++i) {
      unsigned short h, lo;
      split2(xs[i], h, lo);
      ah[i] = (short)h;
      al[i] = (short)lo;
    }
    int wo = jc * 32 + kg * 8;
    bf16x8 bh = *(const bf16x8*)&wxh[wo];
    bf16x8 bl = *(const bf16x8*)&wxl[wo];
    acc0 = __builtin_amdgcn_mfma_f32_16x16x32_bf16(al, bh, acc0, 0, 0, 0);
    acc0 = __builtin_amdgcn_mfma_f32_16x16x32_bf16(ah, bl, acc0, 0, 0, 0);
    acc0 = __builtin_amdgcn_mfma_f32_16x16x32_bf16(ah, bh, acc0, 0, 0, 0);
  }

  // feat part: K=128 in 4 steps; A-frags shared across the 3 scale-segments
  const short* ph = &pan[rowA * PROW];
  const short* pl = &pan[PLO + rowA * PROW];
#pragma unroll
  for (int step = 0; step < 4; ++step) {
    bf16x8 ah = *(const bf16x8*)&ph[step * 32 + kg * 8];
    bf16x8 al = *(const bf16x8*)&pl[step * 32 + kg * 8];
    int fo = jc * 128 + step * 32 + kg * 8;
    {
      bf16x8 bh = *(const bf16x8*)&wfh[fo];
      bf16x8 bl = *(const bf16x8*)&wfl[fo];
      acc0 = __builtin_amdgcn_mfma_f32_16x16x32_bf16(al, bh, acc0, 0, 0, 0);
      acc0 = __builtin_amdgcn_mfma_f32_16x16x32_bf16(ah, bl, acc0, 0, 0, 0);
      acc0 = __builtin_amdgcn_mfma_f32_16x16x32_bf16(ah, bh, acc0, 0, 0, 0);
    }
    {
      bf16x8 bh = *(const bf16x8*)&wfh[4096 + fo];
      bf16x8 bl = *(const bf16x8*)&wfl[4096 + fo];
      acc1 = __builtin_amdgcn_mfma_f32_16x16x32_bf16(al, bh, acc1, 0, 0, 0);
      acc1 = __builtin_amdgcn_mfma_f32_16x16x32_bf16(ah, bl, acc1, 0, 0, 0);
      acc1 = __builtin_amdgcn_mfma_f32_16x16x32_bf16(ah, bh, acc1, 0, 0, 0);
    }
    {
      bf16x8 bh = *(const bf16x8*)&wfh[8192 + fo];
      bf16x8 bl = *(const bf16x8*)&wfl[8192 + fo];
      acc2 = __builtin_amdgcn_mfma_f32_16x16x32_bf16(al, bh, acc2, 0, 0, 0);
      acc2 = __builtin_amdgcn_mfma_f32_16x16x32_bf16(ah, bl, acc2, 0, 0, 0);
      acc2 = __builtin_amdgcn_mfma_f32_16x16x32_bf16(ah, bh, acc2, 0, 0, 0);
    }
  }

  // -------- epilogue: scales per row, bias, relu, store --------
  // C/D layout: col = lane&15, row = (lane>>4)*4 + reg
  {
    int rbase = mt * 16 + kg * 4;          // rows rbase..rbase+3, single node
    int node = node0 + (rbase >> 3);
    float sc1 = scales[node * 3 + 1];
    float sc2 = scales[node * 3 + 2];
    float bias = bl_l[jc & 31];
#pragma unroll
    for (int reg = 0; reg < 4; ++reg) {
      float v = acc0[reg] + sc1 * acc1[reg] + sc2 * acc2[reg] + bias;
      xout[node0 * 256 + (rbase + reg) * 32 + jc] = fmaxf(v, 0.f);
    }
  }
}

// -------------- scoring head: one block per (b, neg) --------------
__global__ void k_score(const float* __restrict__ xL, const float* __restrict__ query,
                        const int* __restrict__ t_index, const float* __restrict__ W1,
                        const float* __restrict__ b1, const float* __restrict__ W2,
                        const float* __restrict__ b2, float* outp) {
  int bn = blockIdx.x;             // b*NEG + neg
  int b = bn >> 5;
  int j = threadIdx.x;             // 64
  __shared__ float f[64];
  int t = t_index[bn];
  f[j] = (j < 32) ? xL[t * BD + b * D + j] : query[b * D + (j - 32)];
  __syncthreads();
  const float* w1r = W1 + j * 64;
  float h = b1[j];
#pragma unroll
  for (int k = 0; k < 64; ++k) h = fmaf(f[k], w1r[k], h);
  h = fmaxf(h, 0.f);
  float p = h * W2[j];
#pragma unroll
  for (int o = 32; o > 0; o >>= 1) p += __shfl_down(p, o, 64);
  if (j == 0) outp[bn] = p + b2[0];
}

} // namespace

extern "C" void kernel_launch(void* const* d_in, const int* in_sizes, int n_in,
                              void* d_out, int out_size, void* d_ws, size_t ws_size,
                              hipStream_t stream) {
  const int* edge_src   = (const int*)d_in[0];
  const int* edge_dst   = (const int*)d_in[1];
  const int* edge_type  = (const int*)d_in[2];
  const int* h_index    = (const int*)d_in[3];
  const int* t_index    = (const int*)d_in[4];
  const int* r_index    = (const int*)d_in[5];
  const float* query_emb= (const float*)d_in[6];
  const float* Wr       = (const float*)d_in[7];
  const float* br       = (const float*)d_in[8];
  const float* Wl       = (const float*)d_in[9];
  const float* bl       = (const float*)d_in[10];
  const float* W1       = (const float*)d_in[11];
  const float* b1       = (const float*)d_in[12];
  const float* W2       = (const float*)d_in[13];
  const float* b2       = (const float*)d_in[14];
  float* outp = (float*)d_out;
  (void)in_sizes; (void)n_in; (void)out_size; (void)ws_size;

  char* w = (char*)d_ws;
  auto alloc = [&](size_t bytes) {
    char* p = w;
    w += (bytes + 511) & ~(size_t)511;
    return p;
  };
  float* x0      = (float*)alloc(sizeof(float) * N * BD);
  float* x1      = (float*)alloc(sizeof(float) * N * BD);
  float* rel     = (float*)alloc(sizeof(float) * L * B * R2 * D);
  short* WT      = (short*)alloc(sizeof(short) * L * WSZ);
  float* query   = (float*)alloc(sizeof(float) * BD);
  float* scales  = (float*)alloc(sizeof(float) * N * 3);
  float* meanacc = (float*)alloc(sizeof(float) * 16);
  int* row_start = (int*)alloc(sizeof(int) * (N + 1));
  int* cnt       = (int*)alloc(sizeof(int) * N);
  int* fill      = (int*)alloc(sizeof(int) * N);
  int* packed    = (int*)alloc(sizeof(int) * E);
  int* bsum      = (int*)alloc(sizeof(int) * 128);
  int* boff      = (int*)alloc(sizeof(int) * 128);

  k_init<<<2048, 256, 0, stream>>>(x0, cnt, meanacc);
  k_query<<<1, 256, 0, stream>>>(r_index, h_index, query_emb, query, x0);
  k_count<<<(E + 255) / 256, 256, 0, stream>>>(edge_dst, cnt);
  k_scanA<<<NSCB, 256, 0, stream>>>(cnt, row_start, bsum);
  k_scanB<<<1, 64, 0, stream>>>(bsum, boff, row_start);
  k_scanC<<<NSCB, 256, 0, stream>>>(row_start, boff);
  k_fill0<<<(N + 255) / 256, 256, 0, stream>>>(fill);
  k_scatter<<<(E + 255) / 256, 256, 0, stream>>>(edge_src, edge_dst, edge_type,
                                                 row_start, fill, packed);
  k_logsum<<<(N + 255) / 256, 256, 0, stream>>>(cnt, meanacc);
  k_scales<<<(N + 255) / 256, 256, 0, stream>>>(cnt, meanacc, scales);
  k_rel<<<(L * B * R2 * D + 255) / 256, 256, 0, stream>>>(query, Wr, br, rel);
  k_wt<<<(L * 13312 + 255) / 256, 256, 0, stream>>>(Wl, WT);

  const float* xin = x0;
  float* xout = x1;
  for (int l = 0; l < L; ++l) {
    k_layer<<<N / NPB, 512, 0, stream>>>(xin, xout,
        rel + (size_t)l * B * R2 * D, WT + (size_t)l * WSZ, bl + l * D,
        scales, row_start, packed, h_index, query);
    const float* t = xout;
    xout = (float*)xin;
    xin = t;
  }
  // L is even -> final activations are back in x0 (== xin after last swap)
  k_score<<<B * NEG, 64, 0, stream>>>(xin, query, t_index, W1, b1, W2, b2, outp);
}

// Round 6
// 566.216 us; speedup vs baseline: 1.2168x; 1.0542x over previous
//
#include <hip/hip_runtime.h>
#include <math.h>

namespace {

constexpr int N   = 20000;
constexpr int E   = 250000;
constexpr int B   = 8;
constexpr int D   = 32;
constexpr int R2  = 100;
constexpr int L   = 6;
constexpr int NEG = 32;
constexpr float EPSF = 1e-6f;

constexpr int BD = B * D;        // 256
constexpr int NPB = 8;           // nodes per block in layer kernel
// bf16 hi/lo feat panels: [64 rows][136] shorts each
constexpr int PROW = 136;
constexpr int PLO  = 64 * PROW;  // lo panel offset (shorts)
// per-layer split-weight block (shorts): [wx_hi 1024 | wx_lo 1024 | wf_hi 12288 | wf_lo 12288]
constexpr int WSZ  = 26624;
constexpr int NSCB = (N + 255) / 256;   // scan blocks = 79
constexpr int PKMAX = 512;       // staged edge-list capacity per block

typedef __attribute__((ext_vector_type(8))) short bf16x8;
typedef __attribute__((ext_vector_type(4))) float f32x4;
typedef _Float16 half4_t __attribute__((ext_vector_type(4)));
typedef _Float16 half8_t __attribute__((ext_vector_type(8)));
typedef float float4_t __attribute__((ext_vector_type(4)));

__device__ inline unsigned short f2bf(float x) {          // RNE f32->bf16
  unsigned int u = __float_as_uint(x);
  unsigned int r = u + 0x7FFF + ((u >> 16) & 1);
  return (unsigned short)(r >> 16);
}
__device__ inline float bf2f(unsigned short h) {
  return __uint_as_float(((unsigned int)h) << 16);
}
__device__ inline void split2(float v, unsigned short& hi, unsigned short& lo) {
  hi = f2bf(v);
  lo = f2bf(v - bf2f(hi));
}

// ---------------- init ----------------
__global__ void k_init(unsigned int* x0i, int* cnt, float* meanacc) {
  int i = blockIdx.x * blockDim.x + threadIdx.x;
  int stride = gridDim.x * blockDim.x;
  for (int t = i; t < N * BD / 2; t += stride) x0i[t] = 0u;  // fp16 x0 = 0
  for (int t = i; t < N; t += stride) cnt[t] = 0;
  if (i == 0) meanacc[0] = 0.f;
}

// query gather + boundary scatter (x0 must be zeroed first); x0 is fp16
__global__ void k_query(const int* __restrict__ r_index, const int* __restrict__ h_index,
                        const float* __restrict__ query_emb, float* query, _Float16* x0) {
  int tid = threadIdx.x;            // 256
  int b = tid >> 5, d = tid & 31;
  float q = query_emb[r_index[b] * D + d];
  query[tid] = q;
  x0[h_index[b] * BD + tid] = (_Float16)q;
}

__global__ void k_count(const int* __restrict__ edge_dst, int* cnt) {
  int e = blockIdx.x * blockDim.x + threadIdx.x;
  if (e < E) atomicAdd(&cnt[edge_dst[e]], 1);
}

// multi-block exclusive scan: A) per-block local scan + block sums
__global__ void k_scanA(const int* __restrict__ cnt, int* row_start, int* bsum) {
  __shared__ int wsum[4];
  int tid = threadIdx.x;            // 256
  int lane = tid & 63, wv = tid >> 6;
  int i = blockIdx.x * 256 + tid;
  int v = (i < N) ? cnt[i] : 0;
  int x = v;
  for (int o = 1; o < 64; o <<= 1) {
    int y = __shfl_up(x, o, 64);
    if (lane >= o) x += y;
  }
  if (lane == 63) wsum[wv] = x;
  __syncthreads();
  int add = 0;
  for (int w = 0; w < wv; ++w) add += wsum[w];
  if (i < N) row_start[i] = x - v + add;     // block-local exclusive
  if (tid == 255) bsum[blockIdx.x] = add + x; // block total
}

// B) scan the block sums (1 wave handles up to 128 blocks)
__global__ void k_scanB(const int* __restrict__ bsum, int* boff, int* row_start) {
  int lane = threadIdx.x;           // 64
  int a0 = (lane < NSCB) ? bsum[lane] : 0;
  int a1 = (64 + lane < NSCB) ? bsum[64 + lane] : 0;
  int x = a0;
  for (int o = 1; o < 64; o <<= 1) {
    int y = __shfl_up(x, o, 64);
    if (lane >= o) x += y;
  }
  int tot0 = __shfl(x, 63, 64);
  int x1 = a1;
  for (int o = 1; o < 64; o <<= 1) {
    int y = __shfl_up(x1, o, 64);
    if (lane >= o) x1 += y;
  }
  if (lane < NSCB) boff[lane] = x - a0;
  if (64 + lane < NSCB) boff[64 + lane] = tot0 + x1 - a1;
  if (lane == 63) row_start[N] = tot0 + __shfl(x1, 63, 64);   // == E
}

// C) add block offsets
__global__ void k_scanC(int* row_start, const int* __restrict__ boff) {
  int i = blockIdx.x * 256 + threadIdx.x;
  if (i < N) row_start[i] += boff[blockIdx.x];
}

// scatter edges into CSR slots; pack src | (type<<16)
__global__ void k_scatter(const int* __restrict__ edge_src, const int* __restrict__ edge_dst,
                          const int* __restrict__ edge_type, const int* __restrict__ row_start,
                          int* fill, int* packed) {
  int e = blockIdx.x * blockDim.x + threadIdx.x;
  if (e < E) {
    int dn = edge_dst[e];
    int pos = atomicAdd(&fill[dn], 1);
    packed[row_start[dn] + pos] = edge_src[e] | (edge_type[e] << 16);
  }
}

__global__ void k_fill0(int* fill) {
  int i = blockIdx.x * blockDim.x + threadIdx.x;
  if (i < N) fill[i] = 0;
}

__global__ void k_logsum(const int* __restrict__ cnt, float* meanacc) {
  int i = blockIdx.x * blockDim.x + threadIdx.x;
  float v = (i < N) ? logf((float)(cnt[i] + 1)) : 0.f;
  for (int o = 32; o > 0; o >>= 1) v += __shfl_down(v, o, 64);
  __shared__ float ws4[4];
  int lane = threadIdx.x & 63, wv = threadIdx.x >> 6;
  if (lane == 0) ws4[wv] = v;
  __syncthreads();
  if (threadIdx.x == 0) atomicAdd(meanacc, ws4[0] + ws4[1] + ws4[2] + ws4[3]);
}

__global__ void k_scales(const int* __restrict__ cnt, const float* __restrict__ meanacc,
                         float* scales) {
  int i = blockIdx.x * blockDim.x + threadIdx.x;
  if (i < N) {
    float m = meanacc[0] / (float)N;
    float s = logf((float)(cnt[i] + 1)) / m;
    scales[i * 3 + 0] = 1.f;
    scales[i * 3 + 1] = s;
    scales[i * 3 + 2] = 1.f / fmaxf(s, 0.01f);
  }
}

// rel (fp16) [l][b][r][d]
__global__ void k_rel(const float* __restrict__ query, const float* __restrict__ Wr,
                      const float* __restrict__ br, _Float16* rel) {
  int o = blockIdx.x * blockDim.x + threadIdx.x;
  if (o >= L * B * R2 * D) return;
  int d = o & 31;
  int r = (o >> 5) % R2;
  int b = (o / (R2 * D)) % B;
  int l = o / (B * R2 * D);
  int rd = r * D + d;
  const float4* wrow = (const float4*)(Wr + ((size_t)l * R2 * D + rd) * D);
  const float* q = query + b * D;
  float acc = br[l * R2 * D + rd];
#pragma unroll
  for (int k = 0; k < 8; ++k) {
    float4 w4 = wrow[k];
    acc = fmaf(q[4 * k + 0], w4.x, acc);
    acc = fmaf(q[4 * k + 1], w4.y, acc);
    acc = fmaf(q[4 * k + 2], w4.z, acc);
    acc = fmaf(q[4 * k + 3], w4.w, acc);
  }
  rel[o] = (_Float16)acc;
}

// split weights to bf16 hi/lo, k-contiguous per output column:
//  k<32 (x part):     wx_[j*32 + k]
//  k=32+3f+s (feat):  wf_[(s*32 + j)*128 + f]
__global__ void k_wt(const float* __restrict__ Wl, short* WT) {
  int o = blockIdx.x * blockDim.x + threadIdx.x;
  if (o >= L * 13312) return;
  int l = o / 13312, t = o % 13312;
  int j = t / 416, k = t % 416;
  float v = Wl[(size_t)l * 13312 + j * 416 + k];
  unsigned short hi, lo;
  split2(v, hi, lo);
  short* wt = WT + (size_t)l * WSZ;
  if (k < 32) {
    int dx = j * 32 + k;
    wt[dx] = (short)hi;
    wt[1024 + dx] = (short)lo;
  } else {
    int u = k - 32;
    int f = u / 3, s = u % 3;
    int df = (s * 32 + j) * 128 + f;
    wt[2048 + df] = (short)hi;
    wt[14336 + df] = (short)lo;
  }
}

// ---- fused layer kernel: 8 nodes / block, 512 threads (8 waves) ----
// x and rel stored fp16 -> gather rows are 512B (halved HBM/L3-side traffic).
// Phase 1 (agg): one wave per node, lane covers 4 channels; block's packed[]
// edge list staged in LDS; 8 edges in flight.
// Phase 2 (GEMM): bf16x3 MFMA 16x16x32, one 16x16 C-tile per wave.
__global__ __launch_bounds__(512, 6) void k_layer(
    const _Float16* __restrict__ xin, _Float16* __restrict__ xout,
    const _Float16* __restrict__ rel_l, const short* __restrict__ WT_l,
    const float* __restrict__ bl_l, const float* __restrict__ scales,
    const int* __restrict__ row_start, const int* __restrict__ packed,
    const int* __restrict__ h_index, const float* __restrict__ query) {
  __shared__ __align__(16) short pan[2 * 64 * PROW];   // 34,816 B
  __shared__ int pkbuf[PKMAX];                         // 2,048 B

  int tid = threadIdx.x;
  int lane = tid & 63;
  int wv = __builtin_amdgcn_readfirstlane(tid >> 6);   // 0..7, wave-uniform
  int node0 = blockIdx.x * NPB;

  // -------- stage block's edge list into LDS --------
  int rs0 = row_start[node0];
  int ecnt = row_start[node0 + NPB] - rs0;
  for (int t = tid; t < ecnt && t < PKMAX; t += 512) pkbuf[t] = packed[rs0 + t];
  __syncthreads();

  // -------- aggregation: wave wv owns node node0+wv --------
  {
    int ch4 = 4 * lane;                 // channels ch4..ch4+3
    int b = lane >> 3;
    int d0 = ch4 & 31;                  // = 4*(lane&7)
    int node = node0 + wv;
    int hb = h_index[b];
    const _Float16* relb4 = rel_l + b * (R2 * D) + d0;
    const _Float16* xch = xin + ch4;
    int rs = row_start[node];
    int cntE = row_start[node + 1] - rs;
    int lrs = rs - rs0;
    // generic pointer: LDS-staged if it fits, else straight from global
    const int* pks = (lrs + cntE <= PKMAX) ? (const int*)&pkbuf[lrs] : &packed[rs];

    float4_t s1 = {0.f, 0.f, 0.f, 0.f}, s2 = {0.f, 0.f, 0.f, 0.f};
    float4_t mx = {-INFINITY, -INFINITY, -INFINITY, -INFINITY};
    float4_t mn = {INFINITY, INFINITY, INFINITY, INFINITY};

    auto acc4 = [&](float4_t xv, float4_t rv) {
#pragma unroll
      for (int c = 0; c < 4; ++c) {
        float m = xv[c] * rv[c];
        s1[c] += m;
        s2[c] = fmaf(m, m, s2[c]);
        mx[c] = fmaxf(mx[c], m);
        mn[c] = fminf(mn[c], m);
      }
    };

    int j = 0;
    for (; j + 7 < cntE; j += 8) {        // 8 edges (16 x 8B loads) in flight
      int pk[8];
#pragma unroll
      for (int u = 0; u < 8; ++u) pk[u] = pks[j + u];
      half4_t xv[8], rv[8];
#pragma unroll
      for (int u = 0; u < 8; ++u) xv[u] = *(const half4_t*)&xch[(pk[u] & 0xFFFF) * BD];
#pragma unroll
      for (int u = 0; u < 8; ++u) rv[u] = *(const half4_t*)&relb4[(pk[u] >> 16) * D];
#pragma unroll
      for (int u = 0; u < 8; ++u)
        acc4(__builtin_convertvector(xv[u], float4_t),
             __builtin_convertvector(rv[u], float4_t));
    }
    for (; j < cntE; ++j) {
      int pk = pks[j];
      half4_t xv = *(const half4_t*)&xch[(pk & 0xFFFF) * BD];
      half4_t rv = *(const half4_t*)&relb4[(pk >> 16) * D];
      acc4(__builtin_convertvector(xv, float4_t),
           __builtin_convertvector(rv, float4_t));
    }
    // boundary self-message
    {
      const float* q4 = &query[ch4];
      bool isb = (hb == node);
      float4_t bnd = {isb ? q4[0] : 0.f, isb ? q4[1] : 0.f,
                      isb ? q4[2] : 0.f, isb ? q4[3] : 0.f};
      float4_t one = {1.f, 1.f, 1.f, 1.f};
      acc4(bnd, one);
    }
    float invdeg = 1.f / (float)(cntE + 1);

    unsigned int hw[8], lw[8];
#pragma unroll
    for (int c = 0; c < 4; ++c) {
      float mean = s1[c] * invdeg, sq = s2[c] * invdeg;
      float sd = sqrtf(fmaxf(sq - mean * mean, EPSF));
      unsigned short h0, l0, h1, l1, h2, l2, h3, l3;
      split2(mean, h0, l0); split2(mx[c], h1, l1);
      split2(mn[c], h2, l2); split2(sd, h3, l3);
      hw[2 * c]     = (unsigned)h0 | ((unsigned)h1 << 16);
      hw[2 * c + 1] = (unsigned)h2 | ((unsigned)h3 << 16);
      lw[2 * c]     = (unsigned)l0 | ((unsigned)l1 << 16);
      lw[2 * c + 1] = (unsigned)l2 | ((unsigned)l3 << 16);
    }
    int r = wv * 8 + b;                  // panel row
    short* dh = &pan[r * PROW + 4 * d0];       // 16B aligned
    short* dl = &pan[PLO + r * PROW + 4 * d0];
    *(uint4*)dh = make_uint4(hw[0], hw[1], hw[2], hw[3]);
    *(uint4*)(dh + 8) = make_uint4(hw[4], hw[5], hw[6], hw[7]);
    *(uint4*)dl = make_uint4(lw[0], lw[1], lw[2], lw[3]);
    *(uint4*)(dl + 8) = make_uint4(lw[4], lw[5], lw[6], lw[7]);
  }
  __syncthreads();

  // -------- GEMM: one 16x16 C-tile per wave, bf16x3 MFMA --------
  int mt = wv >> 1, nt = wv & 1;
  int li = lane & 15, kg = lane >> 4;      // A-row / B-col index, k-group
  int rowA = mt * 16 + li;                 // this lane's A row
  int jc = nt * 16 + li;                   // this lane's B column (output dim)

  const short* wxh = WT_l;
  const short* wxl = WT_l + 1024;
  const short* wfh = WT_l + 2048;
  const short* wfl = WT_l + 14336;

  f32x4 acc0 = {0.f, 0.f, 0.f, 0.f};
  f32x4 acc1 = {0.f, 0.f, 0.f, 0.f};
  f32x4 acc2 = {0.f, 0.f, 0.f, 0.f};

  // x-part (K=32, one step): A from global fp16 (own rows), split in-register
  {
    int xb = node0 * 256 + rowA * 32 + kg * 8;
    half8_t xv = *(const half8_t*)&xin[xb];
    bf16x8 ah, al;
#pragma unroll
    for (int i = 0; i < 8; ++i) {
      unsigned short h, lo;
      split2((float)xv[i], h, lo);     // fp16 within bf16 hi+lo exactly
      ah[i] = (short)h;
      al[i] = (short)lo;
    }
    int wo = jc * 32 + kg * 8;
    bf16x8 bh = *(const bf16x8*)&wxh[wo];
    bf16x8 bl = *(const bf16x8*)&wxl[wo];
    acc0 = __builtin_amdgcn_mfma_f32_16x16x32_bf16(al, bh, acc0, 0, 0, 0);
    acc0 = __builtin_amdgcn_mfma_f32_16x16x32_bf16(ah, bl, acc0, 0, 0, 0);
    acc0 = __builtin_amdgcn_mfma_f32_16x16x32_bf16(ah, bh, acc0, 0, 0, 0);
  }

  // feat part: K=128 in 4 steps; A-frags shared across the 3 scale-segments
  const short* ph = &pan[rowA * PROW];
  const short* pl = &pan[PLO + rowA * PROW];
#pragma unroll
  for (int step = 0; step < 4; ++step) {
    bf16x8 ah = *(const bf16x8*)&ph[step * 32 + kg * 8];
    bf16x8 al = *(const bf16x8*)&pl[step * 32 + kg * 8];
    int fo = jc * 128 + step * 32 + kg * 8;
    {
      bf16x8 bh = *(const bf16x8*)&wfh[fo];
      bf16x8 bl = *(const bf16x8*)&wfl[fo];
      acc0 = __builtin_amdgcn_mfma_f32_16x16x32_bf16(al, bh, acc0, 0, 0, 0);
      acc0 = __builtin_amdgcn_mfma_f32_16x16x32_bf16(ah, bl, acc0, 0, 0, 0);
      acc0 = __builtin_amdgcn_mfma_f32_16x16x32_bf16(ah, bh, acc0, 0, 0, 0);
    }
    {
      bf16x8 bh = *(const bf16x8*)&wfh[4096 + fo];
      bf16x8 bl = *(const bf16x8*)&wfl[4096 + fo];
      acc1 = __builtin_amdgcn_mfma_f32_16x16x32_bf16(al, bh, acc1, 0, 0, 0);
      acc1 = __builtin_amdgcn_mfma_f32_16x16x32_bf16(ah, bl, acc1, 0, 0, 0);
      acc1 = __builtin_amdgcn_mfma_f32_16x16x32_bf16(ah, bh, acc1, 0, 0, 0);
    }
    {
      bf16x8 bh = *(const bf16x8*)&wfh[8192 + fo];
      bf16x8 bl = *(const bf16x8*)&wfl[8192 + fo];
      acc2 = __builtin_amdgcn_mfma_f32_16x16x32_bf16(al, bh, acc2, 0, 0, 0);
      acc2 = __builtin_amdgcn_mfma_f32_16x16x32_bf16(ah, bl, acc2, 0, 0, 0);
      acc2 = __builtin_amdgcn_mfma_f32_16x16x32_bf16(ah, bh, acc2, 0, 0, 0);
    }
  }

  // -------- epilogue: scales per row, bias, relu, fp16 store --------
  // C/D layout: col = lane&15, row = (lane>>4)*4 + reg
  {
    int rbase = mt * 16 + kg * 4;          // rows rbase..rbase+3, single node
    int node = node0 + (rbase >> 3);
    float sc1 = scales[node * 3 + 1];
    float sc2 = scales[node * 3 + 2];
    float bias = bl_l[jc & 31];
#pragma unroll
    for (int reg = 0; reg < 4; ++reg) {
      float v = acc0[reg] + sc1 * acc1[reg] + sc2 * acc2[reg] + bias;
      xout[node0 * 256 + (rbase + reg) * 32 + jc] = (_Float16)fmaxf(v, 0.f);
    }
  }
}

// -------------- scoring head: one block per (b, neg) --------------
__global__ void k_score(const _Float16* __restrict__ xL, const float* __restrict__ query,
                        const int* __restrict__ t_index, const float* __restrict__ W1,
                        const float* __restrict__ b1, const float* __restrict__ W2,
                        const float* __restrict__ b2, float* outp) {
  int bn = blockIdx.x;             // b*NEG + neg
  int b = bn >> 5;
  int j = threadIdx.x;             // 64
  __shared__ float f[64];
  int t = t_index[bn];
  f[j] = (j < 32) ? (float)xL[t * BD + b * D + j] : query[b * D + (j - 32)];
  __syncthreads();
  const float* w1r = W1 + j * 64;
  float h = b1[j];
#pragma unroll
  for (int k = 0; k < 64; ++k) h = fmaf(f[k], w1r[k], h);
  h = fmaxf(h, 0.f);
  float p = h * W2[j];
#pragma unroll
  for (int o = 32; o > 0; o >>= 1) p += __shfl_down(p, o, 64);
  if (j == 0) outp[bn] = p + b2[0];
}

} // namespace

extern "C" void kernel_launch(void* const* d_in, const int* in_sizes, int n_in,
                              void* d_out, int out_size, void* d_ws, size_t ws_size,
                              hipStream_t stream) {
  const int* edge_src   = (const int*)d_in[0];
  const int* edge_dst   = (const int*)d_in[1];
  const int* edge_type  = (const int*)d_in[2];
  const int* h_index    = (const int*)d_in[3];
  const int* t_index    = (const int*)d_in[4];
  const int* r_index    = (const int*)d_in[5];
  const float* query_emb= (const float*)d_in[6];
  const float* Wr       = (const float*)d_in[7];
  const float* br       = (const float*)d_in[8];
  const float* Wl       = (const float*)d_in[9];
  const float* bl       = (const float*)d_in[10];
  const float* W1       = (const float*)d_in[11];
  const float* b1       = (const float*)d_in[12];
  const float* W2       = (const float*)d_in[13];
  const float* b2       = (const float*)d_in[14];
  float* outp = (float*)d_out;
  (void)in_sizes; (void)n_in; (void)out_size; (void)ws_size;

  char* w = (char*)d_ws;
  auto alloc = [&](size_t bytes) {
    char* p = w;
    w += (bytes + 511) & ~(size_t)511;
    return p;
  };
  _Float16* x0   = (_Float16*)alloc(sizeof(_Float16) * N * BD);
  _Float16* x1   = (_Float16*)alloc(sizeof(_Float16) * N * BD);
  _Float16* rel  = (_Float16*)alloc(sizeof(_Float16) * L * B * R2 * D);
  short* WT      = (short*)alloc(sizeof(short) * L * WSZ);
  float* query   = (float*)alloc(sizeof(float) * BD);
  float* scales  = (float*)alloc(sizeof(float) * N * 3);
  float* meanacc = (float*)alloc(sizeof(float) * 16);
  int* row_start = (int*)alloc(sizeof(int) * (N + 1));
  int* cnt       = (int*)alloc(sizeof(int) * N);
  int* fill      = (int*)alloc(sizeof(int) * N);
  int* packed    = (int*)alloc(sizeof(int) * E);
  int* bsum      = (int*)alloc(sizeof(int) * 128);
  int* boff      = (int*)alloc(sizeof(int) * 128);

  k_init<<<2048, 256, 0, stream>>>((unsigned int*)x0, cnt, meanacc);
  k_query<<<1, 256, 0, stream>>>(r_index, h_index, query_emb, query, x0);
  k_count<<<(E + 255) / 256, 256, 0, stream>>>(edge_dst, cnt);
  k_scanA<<<NSCB, 256, 0, stream>>>(cnt, row_start, bsum);
  k_scanB<<<1, 64, 0, stream>>>(bsum, boff, row_start);
  k_scanC<<<NSCB, 256, 0, stream>>>(row_start, boff);
  k_fill0<<<(N + 255) / 256, 256, 0, stream>>>(fill);
  k_scatter<<<(E + 255) / 256, 256, 0, stream>>>(edge_src, edge_dst, edge_type,
                                                 row_start, fill, packed);
  k_logsum<<<(N + 255) / 256, 256, 0, stream>>>(cnt, meanacc);
  k_scales<<<(N + 255) / 256, 256, 0, stream>>>(cnt, meanacc, scales);
  k_rel<<<(L * B * R2 * D + 255) / 256, 256, 0, stream>>>(query, Wr, br, rel);
  k_wt<<<(L * 13312 + 255) / 256, 256, 0, stream>>>(Wl, WT);

  const _Float16* xin = x0;
  _Float16* xout = x1;
  for (int l = 0; l < L; ++l) {
    k_layer<<<N / NPB, 512, 0, stream>>>(xin, xout,
        rel + (size_t)l * B * R2 * D, WT + (size_t)l * WSZ, bl + l * D,
        scales, row_start, packed, h_index, query);
    const _Float16* t = xout;
    xout = (_Float16*)xin;
    xin = t;
  }
  // L is even -> final activations are back in x0 (== xin after last swap)
  k_score<<<B * NEG, 64, 0, stream>>>(xin, query, t_index, W1, b1, W2, b2, outp);
}